// Round 7
// baseline (172.069 us; speedup 1.0000x reference)
//
#include <hip/hip_runtime.h>
#include <math.h>

// Output = segment_softmax over logits that depend ONLY on the inputs part of
// combined @ W_k (the agg/MLP branch is constant per segment -> cancels
// exactly in the segment softmax). wx[d][h] = sum_j Wk[d,h*64+j]*Wq[h,j]/8;
// logit[n,h] = x[n,:].wx[:,h]; per-segment softmax; out[h*N+n].
// Logits are O(0.05) so exp without max-subtraction is safe (validated: same
// absmax as max-subtracted version in rounds 5/6).
//
// Round 7: ONE launch, no workspace.
//  - Per-block segment bounds via 2-round 64-lane parallel probe around the
//    linear estimate s*N/2048 (sigma<=353, window +-2048 ~ 5.8 sigma), with
//    verify + full binary-search fallback.
//  - 2 waves per segment (1024 blocks -> 16 waves/CU TLP).
//  - One pass: e=exp(logit) cached in registers (3 slices/wave = 384 rows),
//    3-row-tiled inner loop reads wx from LDS once per chunk, packed-f32 FMA.

#define NROWS 500000
#define DIM 40
#define NSEG 2048
#define DOTD 64
#define NH 4
#define BLOCK 256
#define SEGB 2               // segments per block (2 waves each)
#define GRID (NSEG / SEGB)   // 1024 blocks
#define MAXSLICE 3           // cached 64-row slices per wave -> 384 rows/segment

typedef float v2f __attribute__((ext_vector_type(2)));

// first index with seg[idx] >= target; wave-cooperative, uniform result
__device__ __forceinline__ int wave_lower_bound(const int* __restrict__ seg,
                                                int target, int lane) {
    if (target <= 0) return 0;
    if (target >= NSEG) return NROWS;
    const int g = (int)(((long long)target * NROWS) >> 11);  // * N / 2048
    // round 1: 64 probes, stride 64, window [g-2048, g+1984]
    int idx = g - 2048 + 64 * lane;
    int c = idx < 0 ? 0 : (idx >= NROWS ? NROWS - 1 : idx);
    bool pred = (idx < 0) || (idx < NROWS && seg[c] < target);
    const int t1 = (int)__popcll(__ballot(pred));
    const int base = g - 2048 + 64 * (t1 - 1) + 1;
    // round 2: 64 probes, stride 1, window [base, base+63]
    idx = base + lane;
    c = idx < 0 ? 0 : (idx >= NROWS ? NROWS - 1 : idx);
    pred = (idx < 0) || (idx < NROWS && seg[c] < target);
    int res = base + (int)__popcll(__ballot(pred));
    // verify (uniform); statistical-tail fallback: full binary search
    bool ok = (res >= 0) && (res <= NROWS);
    if (ok && res > 0) ok = (seg[res - 1] < target);
    if (ok && res < NROWS) ok = ok && (seg[res] >= target);
    if (!ok) {
        int lo = 0, hi = NROWS;
        while (lo < hi) { int mid = (lo + hi) >> 1; if (seg[mid] < target) lo = mid + 1; else hi = mid; }
        res = lo;
    }
    return res;
}

__global__ __launch_bounds__(BLOCK) void fused_kernel(
    const float* __restrict__ x,     // [N, 40]
    const int* __restrict__ seg,     // [N], sorted
    const float* __restrict__ Wk,    // [168, 256]
    const float* __restrict__ Wq,    // [4, 64]
    float* __restrict__ out)         // [4, N]
{
    __shared__ float wxs[DIM][NH];
    __shared__ int bnd[SEGB + 1];
    __shared__ float psum[BLOCK / 64][NH];

    const int tid = (int)threadIdx.x;
    const int lane = tid & 63;
    const int wave = tid >> 6;

    // ---- fold wx (Wk/Wq are L2-hot across 1024 blocks) ----
    if (tid < DIM * NH) {
        const int d = tid >> 2;
        const int h = tid & 3;
        const float* wkp = Wk + d * (NH * DOTD) + h * DOTD;
        const float* wqp = Wq + h * DOTD;
        float acc = 0.f;
        #pragma unroll
        for (int j = 0; j < DOTD; ++j) acc += wkp[j] * wqp[j];
        wxs[d][h] = acc * 0.125f;  // fold 1/sqrt(64)
    }
    // ---- per-block segment bounds: waves 0..2 compute 3 lower_bounds ----
    if (wave <= SEGB) {
        const int b = wave_lower_bound(seg, (int)blockIdx.x * SEGB + wave, lane);
        if (lane == 0) bnd[wave] = b;
    }
    __syncthreads();

    const int sp = wave >> 1;     // which of the block's 2 segments
    const int u  = wave & 1;      // sub-wave within segment (handles slices u, u+2, u+4)
    const int start = bnd[sp];
    const int rows  = bnd[sp + 1] - start;

    float4 e[MAXSLICE];
    int r[MAXSLICE];
    bool val[MAXSLICE];
    #pragma unroll
    for (int t = 0; t < MAXSLICE; ++t) { r[t] = 64 * (u + 2 * t) + lane; val[t] = false; }
    float s0 = 0.f, s1 = 0.f, s2 = 0.f, s3 = 0.f;

    if (rows > 0) {
        const float* xbase = x + (size_t)start * DIM;
        #pragma unroll
        for (int t = 0; t < MAXSLICE; ++t) val[t] = (r[t] < rows);
        v2f a01[MAXSLICE], a23[MAXSLICE];
        #pragma unroll
        for (int t = 0; t < MAXSLICE; ++t) { a01[t] = (v2f){0.f, 0.f}; a23[t] = (v2f){0.f, 0.f}; }
        #pragma unroll
        for (int q = 0; q < DIM / 4; ++q) {
            float4 cch[MAXSLICE];
            #pragma unroll
            for (int t = 0; t < MAXSLICE; ++t) {
                cch[t] = val[t] ? *(const float4*)(xbase + (size_t)r[t] * DIM + 4 * q)
                                : make_float4(0.f, 0.f, 0.f, 0.f);
            }
            #pragma unroll
            for (int d = 0; d < 4; ++d) {
                const v2f w01 = *(const v2f*)&wxs[4 * q + d][0];
                const v2f w23 = *(const v2f*)&wxs[4 * q + d][2];
                #pragma unroll
                for (int t = 0; t < MAXSLICE; ++t) {
                    const float xv = ((const float*)&cch[t])[d];
                    const v2f xs = {xv, xv};
                    a01[t] = __builtin_elementwise_fma(xs, w01, a01[t]);
                    a23[t] = __builtin_elementwise_fma(xs, w23, a23[t]);
                }
            }
        }
        #pragma unroll
        for (int t = 0; t < MAXSLICE; ++t) {
            float4 ev;
            ev.x = __expf(a01[t][0]); ev.y = __expf(a01[t][1]);
            ev.z = __expf(a23[t][0]); ev.w = __expf(a23[t][1]);
            if (!val[t]) ev = make_float4(0.f, 0.f, 0.f, 0.f);
            e[t] = ev;
            s0 += ev.x; s1 += ev.y; s2 += ev.z; s3 += ev.w;
        }
        // safety fallback: rows > 384 (never for this dataset; keeps correctness)
        for (int k = u + 2 * MAXSLICE; 64 * k < rows; k += 2) {
            const int rr = 64 * k + lane;
            if (rr < rows) {
                const float* xr = xbase + (size_t)rr * DIM;
                float a[4] = {0.f, 0.f, 0.f, 0.f};
                for (int dd = 0; dd < DIM; ++dd) {
                    const float xv = xr[dd];
                    a[0] += xv * wxs[dd][0]; a[1] += xv * wxs[dd][1];
                    a[2] += xv * wxs[dd][2]; a[3] += xv * wxs[dd][3];
                }
                s0 += __expf(a[0]); s1 += __expf(a[1]);
                s2 += __expf(a[2]); s3 += __expf(a[3]);
            }
        }
    }

    // ---- wave reduce 4 head-sums, then combine with partner wave via LDS ----
    #pragma unroll
    for (int off = 32; off > 0; off >>= 1) {
        s0 += __shfl_xor(s0, off, 64); s1 += __shfl_xor(s1, off, 64);
        s2 += __shfl_xor(s2, off, 64); s3 += __shfl_xor(s3, off, 64);
    }
    if (lane == 0) {
        psum[wave][0] = s0; psum[wave][1] = s1; psum[wave][2] = s2; psum[wave][3] = s3;
    }
    __syncthreads();

    if (rows > 0) {
        const int pw = wave ^ 1;
        const float rd0 = 1.0f / (s0 + psum[pw][0]);
        const float rd1 = 1.0f / (s1 + psum[pw][1]);
        const float rd2 = 1.0f / (s2 + psum[pw][2]);
        const float rd3 = 1.0f / (s3 + psum[pw][3]);
        #pragma unroll
        for (int t = 0; t < MAXSLICE; ++t) {
            if (val[t]) {
                const int n = start + r[t];
                out[n] = e[t].x * rd0;
                out[NROWS + n] = e[t].y * rd1;
                out[2 * NROWS + n] = e[t].z * rd2;
                out[3 * NROWS + n] = e[t].w * rd3;
            }
        }
        // safety fallback writes (recompute; never taken for this dataset)
        for (int k = u + 2 * MAXSLICE; 64 * k < rows; k += 2) {
            const int rr = 64 * k + lane;
            if (rr < rows) {
                const float* xr = x + (size_t)(start + rr) * DIM;
                float a[4] = {0.f, 0.f, 0.f, 0.f};
                for (int dd = 0; dd < DIM; ++dd) {
                    const float xv = xr[dd];
                    a[0] += xv * wxs[dd][0]; a[1] += xv * wxs[dd][1];
                    a[2] += xv * wxs[dd][2]; a[3] += xv * wxs[dd][3];
                }
                const int n = start + rr;
                out[n] = __expf(a[0]) * rd0;
                out[NROWS + n] = __expf(a[1]) * rd1;
                out[2 * NROWS + n] = __expf(a[2]) * rd2;
                out[3 * NROWS + n] = __expf(a[3]) * rd3;
            }
        }
    }
}

extern "C" void kernel_launch(void* const* d_in, const int* in_sizes, int n_in,
                              void* d_out, int out_size, void* d_ws, size_t ws_size,
                              hipStream_t stream) {
    const float* x  = (const float*)d_in[0];
    const int* seg  = (const int*)d_in[1];
    const float* Wk = (const float*)d_in[11];
    const float* Wq = (const float*)d_in[12];
    float* out = (float*)d_out;
    hipLaunchKernelGGL(fused_kernel, dim3(GRID), dim3(BLOCK), 0, stream,
                       x, seg, Wk, Wq, out);
}